// Round 3
// baseline (165.489 us; speedup 1.0000x reference)
//
#include <hip/hip_runtime.h>
#include <hip/hip_bf16.h>

// Problem constants (match reference)
constexpr int kB    = 8;
constexpr int kN    = 512;
constexpr int kFIN  = 256;
constexpr int kFOUT = 128;
constexpr int kNE   = 10;          // emb has kNE+1 rows, row 0 = padding (zeros)
constexpr float kALPHA = 0.2f;
constexpr float kNEG   = -9e15f;

// ---------------------------------------------------------------------------
// Kernel 1: typed projection  h[row,o] = sum_t mask[t,row]*(x@W_t + b_t)
// Grid: 512 blocks = 256 row-blocks x 2 col-halves. 256 threads.
// Thread = (o4 = tid&15 -> 4 consecutive outs, r = tid>>4 -> 1 row).
// float4 W loads; xs padded to stride 260 so the 4 rows a wave reads land in
// different banks ((r*260+i)%32 steps by 4 per row).
// ---------------------------------------------------------------------------
constexpr int PR = 16;

__global__ __launch_bounds__(256) void proj_kernel(
    const float* __restrict__ node_rep,  // (B*N, FIN)
    const float* __restrict__ mask,      // (T, B*N)
    const float* __restrict__ W,         // (T, FIN, FOUT)
    const float* __restrict__ bias,      // (T, FOUT)
    float* __restrict__ h)               // (B*N, FOUT)
{
    __shared__ float xs[PR][kFIN + 4];

    const int tid  = threadIdx.x;
    const int rb   = blockIdx.x >> 1;
    const int ch   = blockIdx.x & 1;
    const int row0 = rb * PR;
    const int o    = ch * 64 + (tid & 15) * 4;
    const int r    = tid >> 4;

    for (int idx = tid; idx < PR * kFIN; idx += 256) {
        int rr = idx >> 8;
        int i  = idx & (kFIN - 1);
        xs[rr][i] = node_rep[(row0 + rr) * kFIN + i];
    }
    __syncthreads();

    float4 a0 = {0,0,0,0}, a1v = {0,0,0,0}, a2v = {0,0,0,0};
    #pragma unroll 2
    for (int i = 0; i < kFIN; ++i) {
        float  x  = xs[r][i];
        float4 w0 = *(const float4*)&W[(0 * kFIN + i) * kFOUT + o];
        float4 w1 = *(const float4*)&W[(1 * kFIN + i) * kFOUT + o];
        float4 w2 = *(const float4*)&W[(2 * kFIN + i) * kFOUT + o];
        a0.x  = fmaf(w0.x, x, a0.x);  a0.y  = fmaf(w0.y, x, a0.y);
        a0.z  = fmaf(w0.z, x, a0.z);  a0.w  = fmaf(w0.w, x, a0.w);
        a1v.x = fmaf(w1.x, x, a1v.x); a1v.y = fmaf(w1.y, x, a1v.y);
        a1v.z = fmaf(w1.z, x, a1v.z); a1v.w = fmaf(w1.w, x, a1v.w);
        a2v.x = fmaf(w2.x, x, a2v.x); a2v.y = fmaf(w2.y, x, a2v.y);
        a2v.z = fmaf(w2.z, x, a2v.z); a2v.w = fmaf(w2.w, x, a2v.w);
    }

    const int row = row0 + r;
    const float m0 = mask[row];
    const float m1 = mask[kB * kN + row];
    const float m2 = mask[2 * kB * kN + row];
    const float4 b0 = *(const float4*)&bias[o];
    const float4 b1 = *(const float4*)&bias[kFOUT + o];
    const float4 b2 = *(const float4*)&bias[2 * kFOUT + o];

    float4 hv;
    hv.x = m0 * (a0.x + b0.x) + m1 * (a1v.x + b1.x) + m2 * (a2v.x + b2.x);
    hv.y = m0 * (a0.y + b0.y) + m1 * (a1v.y + b1.y) + m2 * (a2v.y + b2.y);
    hv.z = m0 * (a0.z + b0.z) + m1 * (a1v.z + b1.z) + m2 * (a2v.z + b2.z);
    hv.w = m0 * (a0.w + b0.w) + m1 * (a1v.w + b1.w) + m2 * (a2v.w + b2.w);
    *(float4*)&h[(size_t)row * kFOUT + o] = hv;
}

// ---------------------------------------------------------------------------
// Kernel 2: s1[row]=h.a1+a_b, s2[row]=h.a2 (wave per row) + emb.a2 table
// Grid: B*N/4 + 1 blocks; last block computes emb_a2.
// ---------------------------------------------------------------------------
__global__ __launch_bounds__(256) void sk_kernel(
    const float* __restrict__ h,
    const float* __restrict__ a1,
    const float* __restrict__ a2,
    const float* __restrict__ a_b,
    const float* __restrict__ emb,   // (NE+1, FOUT)
    float* __restrict__ s1,
    float* __restrict__ s2,
    float* __restrict__ emb_a2)
{
    const int tid = threadIdx.x;

    if (blockIdx.x == (kB * kN) / 4) {
        // emb_a2: 16 threads per e-row, 16 rows covered (need 11)
        const int e = tid >> 4, l = tid & 15;
        if (e <= kNE) {
            float p = 0.f;
            #pragma unroll
            for (int k = 0; k < 8; ++k)
                p += emb[e * kFOUT + l + k * 16] * a2[l + k * 16];
            #pragma unroll
            for (int off = 8; off; off >>= 1) p += __shfl_xor(p, off);
            if (l == 0) emb_a2[e] = p;
        }
        return;
    }

    const int row  = blockIdx.x * 4 + (tid >> 6);
    const int lane = tid & 63;
    const float v0 = h[(size_t)row * kFOUT + lane];
    const float v1 = h[(size_t)row * kFOUT + 64 + lane];
    float p1 = v0 * a1[lane] + v1 * a1[64 + lane];
    float p2 = v0 * a2[lane] + v1 * a2[64 + lane];
    #pragma unroll
    for (int off = 32; off; off >>= 1) {
        p1 += __shfl_down(p1, off);
        p2 += __shfl_down(p2, off);
    }
    if (lane == 0) {
        s1[row] = p1 + a_b[0];
        s2[row] = p2;
    }
}

// ---------------------------------------------------------------------------
// Kernel 3: scores + softmax + edge-type histogram + dense attn@h + ELU
//   out[i,f] = elu( sum_j attn[i,j]*h[j,f]  +  sum_e wsum[i,e]*emb[e,f] )
// TI=4 rows/block, 256 threads, grid B*(N/4)=1024 -> 4 blocks/CU.
// ---------------------------------------------------------------------------
constexpr int TI = 4;

__global__ __launch_bounds__(256) void attn_kernel(
    const int*   __restrict__ adj,     // (B, N, N)
    const float* __restrict__ emb,     // (NE+1, FOUT)
    const float* __restrict__ h,       // (B*N, FOUT)
    const float* __restrict__ s1,      // (B*N), a_b folded in
    const float* __restrict__ s2,      // (B*N)
    const float* __restrict__ emb_a2g, // (NE+1)
    float* __restrict__ out)           // (B*N, FOUT)
{
    __shared__ float sc[TI][kN];        // 8 KB: scores -> attn
    __shared__ int   adjs[TI][kN];      // 8 KB: adj tile; reused as scratch
    __shared__ float wsum_s[TI][16];
    __shared__ float ea2[kNE + 1];

    const int tid = threadIdx.x;
    const int b   = blockIdx.x >> 7;          // / (kN/TI)
    const int i0  = (blockIdx.x & 127) * TI;

    if (tid < kNE + 1) ea2[tid] = emb_a2g[tid];
    __syncthreads();

    // scores (r is wave-uniform each iteration: r = iter>>1)
    for (int idx = tid; idx < TI * kN; idx += 256) {
        int r = idx >> 9;
        int j = idx & (kN - 1);
        int a = adj[((size_t)(b * kN + i0 + r)) * kN + j];
        float s = s1[b * kN + i0 + r] + s2[b * kN + j] + ea2[a];
        s = (s > 0.f) ? s : kALPHA * s;
        sc[r][j]   = (a > 0) ? s : kNEG;
        adjs[r][j] = a;
    }
    __syncthreads();

    // softmax + 10-bin histogram: wave per row
    const int wave = tid >> 6, lane = tid & 63;
    {
        const int r = wave;
        float v[8]; int av[8];
        #pragma unroll
        for (int k = 0; k < 8; ++k) {
            v[k]  = sc[r][lane + k * 64];
            av[k] = adjs[r][lane + k * 64];
        }
        float m = v[0];
        #pragma unroll
        for (int k = 1; k < 8; ++k) m = fmaxf(m, v[k]);
        #pragma unroll
        for (int off = 32; off; off >>= 1) m = fmaxf(m, __shfl_xor(m, off));
        float sum = 0.f;
        #pragma unroll
        for (int k = 0; k < 8; ++k) { v[k] = __expf(v[k] - m); sum += v[k]; }
        #pragma unroll
        for (int off = 32; off; off >>= 1) sum += __shfl_xor(sum, off);
        const float inv = 1.0f / sum;
        #pragma unroll
        for (int k = 0; k < 8; ++k) {
            v[k] *= inv;
            sc[r][lane + k * 64] = v[k];
        }
        // histogram over edge types 1..10 (emb[0]=0 -> skip bin 0)
        for (int e = 1; e <= kNE; ++e) {
            float p = 0.f;
            #pragma unroll
            for (int k = 0; k < 8; ++k) p += (av[k] == e) ? v[k] : 0.f;
            #pragma unroll
            for (int off = 32; off; off >>= 1) p += __shfl_xor(p, off);
            if (lane == 0) wsum_s[r][e] = p;
        }
    }
    __syncthreads();

    // dense attn @ h: thread = (f4 = tid&31 -> 4 feats, rs = (tid>>5)&3 -> row,
    // kh = tid>>7 -> j-half). h rows are L2-resident (2 MB total).
    const int f4 = (tid & 31) * 4;
    const int rs = (tid >> 5) & 3;
    const int kh = tid >> 7;
    const float* hb = h + ((size_t)b * kN) * kFOUT + f4;

    float4 acc = {0,0,0,0};
    const int j0 = kh * 256;
    #pragma unroll 4
    for (int j = j0; j < j0 + 256; ++j) {
        float  w  = sc[rs][j];
        float4 hv = *(const float4*)&hb[(size_t)j * kFOUT];
        acc.x = fmaf(w, hv.x, acc.x);
        acc.y = fmaf(w, hv.y, acc.y);
        acc.z = fmaf(w, hv.z, acc.z);
        acc.w = fmaf(w, hv.w, acc.w);
    }

    // combine halves through LDS (reuse adjs area; it is dead now)
    float* scratch = (float*)adjs;
    if (kh == 1) *(float4*)&scratch[(rs * 32 + (tid & 31)) * 4] = acc;
    __syncthreads();
    if (kh == 0) {
        float4 o2 = *(const float4*)&scratch[(rs * 32 + (tid & 31)) * 4];
        acc.x += o2.x; acc.y += o2.y; acc.z += o2.z; acc.w += o2.w;
        // edge-type correction: sum_e wsum[e] * emb[e, f4..f4+3]
        for (int e = 1; e <= kNE; ++e) {
            float  wv = wsum_s[rs][e];
            float4 ev = *(const float4*)&emb[e * kFOUT + f4];
            acc.x = fmaf(wv, ev.x, acc.x);
            acc.y = fmaf(wv, ev.y, acc.y);
            acc.z = fmaf(wv, ev.z, acc.z);
            acc.w = fmaf(wv, ev.w, acc.w);
        }
        // ELU
        acc.x = (acc.x > 0.f) ? acc.x : expm1f(acc.x);
        acc.y = (acc.y > 0.f) ? acc.y : expm1f(acc.y);
        acc.z = (acc.z > 0.f) ? acc.z : expm1f(acc.z);
        acc.w = (acc.w > 0.f) ? acc.w : expm1f(acc.w);
        *(float4*)&out[((size_t)b * kN + i0 + rs) * kFOUT + f4] = acc;
    }
}

// ---------------------------------------------------------------------------
extern "C" void kernel_launch(void* const* d_in, const int* in_sizes, int n_in,
                              void* d_out, int out_size, void* d_ws, size_t ws_size,
                              hipStream_t stream) {
    const float* node_rep = (const float*)d_in[0];
    const float* mask     = (const float*)d_in[1];
    const int*   adj      = (const int*)  d_in[2];
    const float* W        = (const float*)d_in[3];
    const float* bias     = (const float*)d_in[4];
    const float* a1       = (const float*)d_in[5];
    const float* a2       = (const float*)d_in[6];
    const float* a_b      = (const float*)d_in[7];
    const float* emb      = (const float*)d_in[8];
    float* out = (float*)d_out;

    float* ws     = (float*)d_ws;
    float* h      = ws;                            // B*N*FOUT
    float* s1     = h + (size_t)kB * kN * kFOUT;   // B*N
    float* s2     = s1 + kB * kN;                  // B*N
    float* emb_a2 = s2 + kB * kN;                  // 16

    proj_kernel<<<512, 256, 0, stream>>>(node_rep, mask, W, bias, h);
    sk_kernel<<<(kB * kN) / 4 + 1, 256, 0, stream>>>(h, a1, a2, a_b, emb, s1, s2, emb_a2);
    attn_kernel<<<kB * (kN / TI), 256, 0, stream>>>(adj, emb, h, s1, s2, emb_a2, out);
}